// Round 6
// baseline (176.559 us; speedup 1.0000x reference)
//
#include <hip/hip_runtime.h>
#include <hip/hip_bf16.h>
#include <hip/hip_cooperative_groups.h>

namespace cg = cooperative_groups;

// Decoder: x = z @ softplus(W_mix)^T ; per-channel MLP 1->H->H->1 with tanh.
// N=16384, L=16, D=128, H=64.
// Round 6: single cooperative kernel. Phase 1 (512 blocks = (d, 256-pt tile))
// tabulates f_d at 1024 pts (step 1/16, [-32,32)) via the MFMA pipeline into
// ws; __threadfence + grid.sync (device scope, cross-XCD safe); phase 2
// (block = 16 channels x 256 samples) stages the 16 tables (64 KB,
// contiguous) into LDS and interpolates -- z in registers, coalesced stores.
// Round-5 counters: harness ws-poison (~40us fill) + restores are the ~78us
// floor; this round attacks the remaining ~12us (build 8 -> ~4, decode
// 4 -> ~2, one launch gap removed).

#define N_SAMPLES 16384
#define L_DIM 16
#define D_DIM 128
#define H_DIM 64
#define W2T_STRIDE 72    // ushort elems; 144 B rows, 16B-aligned
#define TAB_N 4096       // tanh LUT: [-4,4], step 1/512
#define FT_PTS 1024      // f-table points per channel
#define FT_SCALE 16.0f   // idx = x*16 + 512; step 1/16 over [-32,32)
#define FT_OFF 512.0f
#define SMEM_BYTES 66560 // max(build ~35.5 KB, decode 64 KB tab + 1 KB sp)

typedef __attribute__((ext_vector_type(8))) short short8;
typedef __attribute__((ext_vector_type(4))) float float4v;

__device__ __forceinline__ float fast_tanh(float x) {
    float e = __expf(2.0f * x);
    return 1.0f - 2.0f * __builtin_amdgcn_rcpf(1.0f + e);
}

__device__ __forceinline__ unsigned short f2bf(float f) {
    union { float f; unsigned int u; } v; v.f = f;
    unsigned int r = (v.u + 0x7fffu + ((v.u >> 16) & 1u)) >> 16;   // RNE
    return (unsigned short)r;
}

__device__ __forceinline__ float softplus_f(float w) {
    return (w > 20.0f) ? w : log1pf(__expf(w));
}

// =====================================================================
// Phase 1: tabulate f_d at x = gi/16 - 32, gi in [0,1024).
// bx in [0,512): d = bx>>2, tile = bx&3. LDS carve (from smem base):
//   [0,16384)      s_tabf  f32 tanh LUT
//   [16384,24576)  s_tabh  bf16 tanh LUT
//   [24576,33792)  s_w2t   W2^T bf16, stride 72
//   [33792,34048)  s_w1s   512*W1
//   [34048,34304)  s_b1s   512*b1+2048
//   [34304,34560)  s_c2    512*b2+2048
//   [34560,34816)  s_W3
// =====================================================================
__device__ __forceinline__ void build_phase(
    int bx, int tid, char* smem,
    const float* __restrict__ W1, const float* __restrict__ b1,
    const float* __restrict__ W2, const float* __restrict__ b2,
    const float* __restrict__ W3, const float* __restrict__ b3,
    float* __restrict__ ftab)
{
    const int d      = bx >> 2;
    const int gBase  = (bx & 3) * 256;
    const int lane   = tid & 63;
    const int waveId = tid >> 6;
    const int quad   = lane >> 4;
    const int l15    = lane & 15;

    float* s_tabf = (float*)smem;
    unsigned short* s_tabh = (unsigned short*)(smem + 16384);
    unsigned short* s_w2t  = (unsigned short*)(smem + 24576);
    float* s_w1s = (float*)(smem + 33792);
    float* s_b1s = (float*)(smem + 34048);
    float* s_c2  = (float*)(smem + 34304);
    float* s_W3  = (float*)(smem + 34560);

    // in-block tanh LUT build (16 evals/thread)
    #pragma unroll
    for (int it = 0; it < TAB_N / 256; ++it) {
        int i = tid + it * 256;
        float c = ((float)(i - 2048) + 0.5f) * (1.0f / 512.0f);
        float v = fast_tanh(c);
        s_tabf[i] = v;
        s_tabh[i] = f2bf(v);
    }

    if (tid < 64) {
        s_w1s[tid] = W1[d * H_DIM + tid] * 512.0f;
        s_b1s[tid] = b1[d * H_DIM + tid] * 512.0f + 2048.0f;
    } else if (tid < 128) {
        int h = tid - 64;
        s_c2[h] = b2[d * H_DIM + h] * 512.0f + 2048.0f;
        s_W3[h] = W3[d * H_DIM + h];
    }
    {
        const float* gW2 = W2 + (size_t)d * H_DIM * H_DIM;   // [h][col]
        #pragma unroll
        for (int i = 0; i < 16; ++i) {
            int idx = tid + i * 256;
            int h = idx >> 6, c = idx & 63;
            s_w2t[c * W2T_STRIDE + h] = f2bf(gW2[idx]);
        }
    }
    __syncthreads();

    float x = (float)(gBase + tid) * (1.0f / FT_SCALE) - 32.0f;

    float xm[4];
    #pragma unroll
    for (int mt = 0; mt < 4; ++mt) xm[mt] = __shfl(x, mt * 16 + l15, 64);

    // layer 1 -> A fragments via bf16 tanh LUT: A[m=l15][k=quad*8+j]
    short8 afrag[4][2];
    #pragma unroll
    for (int ks = 0; ks < 2; ++ks) {
        float w1v[8], b1v[8];
        #pragma unroll
        for (int j = 0; j < 8; ++j) {
            int k = ks * 32 + quad * 8 + j;
            w1v[j] = s_w1s[k];
            b1v[j] = s_b1s[k];
        }
        #pragma unroll
        for (int mt = 0; mt < 4; ++mt) {
            unsigned short hb[8];
            #pragma unroll
            for (int j = 0; j < 8; ++j) {
                float idxf = fmaf(xm[mt], w1v[j], b1v[j]);
                idxf = fminf(fmaxf(idxf, 0.0f), 4095.0f);
                hb[j] = s_tabh[(unsigned int)idxf];
            }
            union { unsigned int u[4]; short8 s; } fr;
            #pragma unroll
            for (int p = 0; p < 4; ++p)
                fr.u[p] = (unsigned int)hb[2*p] | ((unsigned int)hb[2*p+1] << 16);
            afrag[mt][ks] = fr.s;
        }
    }

    short8 bfrag[4][2];
    #pragma unroll
    for (int nt = 0; nt < 4; ++nt)
        #pragma unroll
        for (int ks = 0; ks < 2; ++ks)
            bfrag[nt][ks] = *(const short8*)
                &s_w2t[(nt * 16 + l15) * W2T_STRIDE + ks * 32 + quad * 8];

    float4v acc[4][4];
    #pragma unroll
    for (int mt = 0; mt < 4; ++mt)
        #pragma unroll
        for (int nt = 0; nt < 4; ++nt) {
            float4v c = {0.0f, 0.0f, 0.0f, 0.0f};
            c = __builtin_amdgcn_mfma_f32_16x16x32_bf16(afrag[mt][0], bfrag[nt][0], c, 0, 0, 0);
            c = __builtin_amdgcn_mfma_f32_16x16x32_bf16(afrag[mt][1], bfrag[nt][1], c, 0, 0, 0);
            acc[mt][nt] = c;
        }

    float w3v[4], c2v[4];
    #pragma unroll
    for (int nt = 0; nt < 4; ++nt) {
        int col = nt * 16 + l15;
        w3v[nt] = s_W3[col];
        c2v[nt] = s_c2[col];
    }

    float psum[4][4];
    #pragma unroll
    for (int mt = 0; mt < 4; ++mt)
        #pragma unroll
        for (int r = 0; r < 4; ++r) psum[mt][r] = 0.0f;

    #pragma unroll
    for (int mt = 0; mt < 4; ++mt)
        #pragma unroll
        for (int nt = 0; nt < 4; ++nt)
            #pragma unroll
            for (int r = 0; r < 4; ++r) {
                float idxf = fmaf(acc[mt][nt][r], 512.0f, c2v[nt]);
                idxf = fminf(fmaxf(idxf, 0.0f), 4095.0f);
                psum[mt][r] += s_tabf[(unsigned int)idxf] * w3v[nt];
            }

    #pragma unroll
    for (int mask = 1; mask < 16; mask <<= 1)
        #pragma unroll
        for (int mt = 0; mt < 4; ++mt)
            #pragma unroll
            for (int r = 0; r < 4; ++r)
                psum[mt][r] += __shfl_xor(psum[mt][r], mask, 64);

    const float bias = b3[d];   // wave-uniform scalar load
    #pragma unroll
    for (int mt = 0; mt < 4; ++mt)
        #pragma unroll
        for (int r = 0; r < 4; ++r)
            if (l15 == mt * 4 + r) {
                int row = mt * 16 + quad * 4 + r;
                int gi = gBase + waveId * 64 + row;
                ftab[d * FT_PTS + gi] = psum[mt][r] + bias;
            }
}

// =====================================================================
// Phase 2: decode. bx in [0,512): sgrp = bx&63 (256 samples),
// cgrp = bx>>6 (16 channels). 16 tables (contiguous 64 KB) -> LDS;
// z in registers; per-thread 64 B contiguous stores.
// =====================================================================
__device__ __forceinline__ void decode_phase(
    int bx, int tid, char* smem,
    const float* __restrict__ z, const float* __restrict__ W_mix,
    const float* __restrict__ ftab, float* __restrict__ out)
{
    const int n0 = (bx & 63) * 256;
    const int c0 = (bx >> 6) * 16;

    float* s_tab = (float*)smem;             // [16][FT_PTS], 64 KB
    float* s_sp  = (float*)(smem + 65536);   // [16][16]

    const float4* gt = (const float4*)(ftab + (size_t)c0 * FT_PTS);
    float4* st = (float4*)s_tab;
    #pragma unroll
    for (int j = 0; j < 16; ++j)
        st[tid + j * 256] = gt[tid + j * 256];

    {
        int c = tid >> 4, l = tid & 15;
        s_sp[tid] = softplus_f(W_mix[(c0 + c) * L_DIM + l]);
    }
    __syncthreads();

    const int n = n0 + tid;
    float4 zz[4];
    const float4* zp = (const float4*)(z + (size_t)n * L_DIM);
    #pragma unroll
    for (int i = 0; i < 4; ++i) zz[i] = zp[i];

    float o[16];
    #pragma unroll
    for (int c = 0; c < 16; ++c) {
        const float4* spv = (const float4*)(s_sp + c * 16);  // wave-uniform
        float x = 0.0f;
        #pragma unroll
        for (int i = 0; i < 4; ++i) {
            float4 s = spv[i];
            x = fmaf(zz[i].x, s.x, x);
            x = fmaf(zz[i].y, s.y, x);
            x = fmaf(zz[i].z, s.z, x);
            x = fmaf(zz[i].w, s.w, x);
        }
        float idxf = fmaf(x, FT_SCALE, FT_OFF);
        idxf = fminf(fmaxf(idxf, 0.0f), (float)(FT_PTS - 2));
        int i0 = (int)idxf;
        float fr = idxf - (float)i0;
        const float* tb = s_tab + c * FT_PTS;
        float v0 = tb[i0];
        float v1 = tb[i0 + 1];
        o[c] = fmaf(v1 - v0, fr, v0);
    }

    float4* op = (float4*)(out + (size_t)n * D_DIM + c0);
    #pragma unroll
    for (int q = 0; q < 4; ++q) {
        float4 v;
        v.x = o[4*q+0]; v.y = o[4*q+1]; v.z = o[4*q+2]; v.w = o[4*q+3];
        op[q] = v;
    }
}

// =====================================================================
// Fused cooperative kernel + standalone fallbacks
// =====================================================================
__global__ __launch_bounds__(256, 2) void decoder_fused(
    const float* __restrict__ z, const float* __restrict__ W_mix,
    const float* __restrict__ W1, const float* __restrict__ b1,
    const float* __restrict__ W2, const float* __restrict__ b2,
    const float* __restrict__ W3, const float* __restrict__ b3,
    float* __restrict__ out, float* __restrict__ ws)
{
    extern __shared__ char smem[];
    build_phase(blockIdx.x, threadIdx.x, smem, W1, b1, W2, b2, W3, b3, ws);
    __threadfence();                 // release ftab stores (device scope)
    cg::this_grid().sync();          // grid-wide barrier (cross-XCD safe)
    decode_phase(blockIdx.x, threadIdx.x, smem, z, W_mix, ws, out);
}

__global__ __launch_bounds__(256, 2) void build_k(
    const float* __restrict__ W1, const float* __restrict__ b1,
    const float* __restrict__ W2, const float* __restrict__ b2,
    const float* __restrict__ W3, const float* __restrict__ b3,
    float* __restrict__ ws)
{
    extern __shared__ char smem[];
    build_phase(blockIdx.x, threadIdx.x, smem, W1, b1, W2, b2, W3, b3, ws);
}

__global__ __launch_bounds__(256, 2) void decode_k(
    const float* __restrict__ z, const float* __restrict__ W_mix,
    const float* __restrict__ ws, float* __restrict__ out)
{
    extern __shared__ char smem[];
    decode_phase(blockIdx.x, threadIdx.x, smem, z, W_mix, ws, out);
}

extern "C" void kernel_launch(void* const* d_in, const int* in_sizes, int n_in,
                              void* d_out, int out_size, void* d_ws, size_t ws_size,
                              hipStream_t stream) {
    const float* z     = (const float*)d_in[0];
    const float* W_mix = (const float*)d_in[1];
    const float* W1    = (const float*)d_in[2];
    const float* b1    = (const float*)d_in[3];
    const float* W2    = (const float*)d_in[4];
    const float* b2    = (const float*)d_in[5];
    const float* W3    = (const float*)d_in[6];
    const float* b3    = (const float*)d_in[7];
    float* out = (float*)d_out;
    float* ws  = (float*)d_ws;

    const size_t need = (size_t)D_DIM * FT_PTS * 4;
    if (ws_size >= need) {
        void* args[] = {(void*)&z, (void*)&W_mix, (void*)&W1, (void*)&b1,
                        (void*)&W2, (void*)&b2, (void*)&W3, (void*)&b3,
                        (void*)&out, (void*)&ws};
        hipError_t e = hipLaunchCooperativeKernel(
            (const void*)decoder_fused, dim3(512), dim3(256),
            args, SMEM_BYTES, stream);
        if (e != hipSuccess) {
            // fallback: two plain launches (same phases, no grid sync)
            build_k<<<dim3(512), dim3(256), SMEM_BYTES, stream>>>(
                W1, b1, W2, b2, W3, b3, ws);
            decode_k<<<dim3(512), dim3(256), SMEM_BYTES, stream>>>(
                z, W_mix, ws, out);
        }
    } else {
        // ws too small (should not happen): two-pass still needs ftab; as a
        // last resort run build into out's tail? Not possible -- use a tiny
        // grid direct fallback via decode of per-block-built tables:
        // build_k/decode_k require ws; emergency path: reuse out buffer is
        // unsafe. Launch the two-kernel path anyway only if ws fits ftab;
        // otherwise compute directly (slow path).
        build_k<<<dim3(512), dim3(256), SMEM_BYTES, stream>>>(
            W1, b1, W2, b2, W3, b3, ws);
        decode_k<<<dim3(512), dim3(256), SMEM_BYTES, stream>>>(
            z, W_mix, ws, out);
    }
}

// Round 7
// 86.200 us; speedup vs baseline: 2.0482x; 2.0482x over previous
//
#include <hip/hip_runtime.h>
#include <hip/hip_bf16.h>

// Decoder: x = z @ softplus(W_mix)^T ; per-channel MLP 1->H->H->1 with tanh.
// N=16384, L=16, D=128, H=64.
// Round 7: out[n,d] = f_d(x[n,d]) scalar-function factorization.
//   build_k : 512 blocks (d, 256-pt tile) tabulate f_d at 1024 pts
//             (step 1/16, [-32,32)) via bf16 MFMA + in-LDS tanh LUTs.
//   decode_k: 512 blocks (256 samples x 16 channels); the 16 channels'
//             tables (64 KB contiguous) staged to LDS, z in registers,
//             16-float contiguous stores per thread.
// Round-6 lesson (measured): cg::grid().sync() on 512 blocks costs ~80us
// (software barrier spin) -- NEVER worth saving one ~2us graph edge. Two
// plain launches restored. Round-6 counters validated both phases' memory
// behavior (WRITE_SIZE ~9.2MB ~= ideal 8.4MB).
// Harness floor: ~40us d_ws re-poison fill + restores + gaps ~= 78us.

#define N_SAMPLES 16384
#define L_DIM 16
#define D_DIM 128
#define H_DIM 64
#define W2T_STRIDE 72    // ushort elems; 144 B rows, 16B-aligned
#define TAB_N 4096       // tanh LUT: [-4,4], step 1/512
#define FT_PTS 1024      // f-table points per channel
#define FT_SCALE 16.0f   // idx = x*16 + 512; step 1/16 over [-32,32)
#define FT_OFF 512.0f

typedef __attribute__((ext_vector_type(8))) short short8;
typedef __attribute__((ext_vector_type(4))) float float4v;

__device__ __forceinline__ float fast_tanh(float x) {
    float e = __expf(2.0f * x);
    return 1.0f - 2.0f * __builtin_amdgcn_rcpf(1.0f + e);
}

__device__ __forceinline__ unsigned short f2bf(float f) {
    union { float f; unsigned int u; } v; v.f = f;
    unsigned int r = (v.u + 0x7fffu + ((v.u >> 16) & 1u)) >> 16;   // RNE
    return (unsigned short)r;
}

__device__ __forceinline__ float softplus_f(float w) {
    return (w > 20.0f) ? w : log1pf(__expf(w));
}

// =====================================================================
// build_k: tabulate f_d at x = gi/16 - 32, gi in [0,1024).
// blockIdx.x in [0,512): d = bx>>2, tile = bx&3.
// =====================================================================
__global__ __launch_bounds__(256, 2) void build_k(
    const float* __restrict__ W1, const float* __restrict__ b1,
    const float* __restrict__ W2, const float* __restrict__ b2,
    const float* __restrict__ W3, const float* __restrict__ b3,
    float* __restrict__ ftab)
{
    const int bx     = blockIdx.x;
    const int tid    = threadIdx.x;
    const int d      = bx >> 2;
    const int gBase  = (bx & 3) * 256;
    const int lane   = tid & 63;
    const int waveId = tid >> 6;
    const int quad   = lane >> 4;
    const int l15    = lane & 15;

    __shared__ __align__(16) float s_tabf[TAB_N];          // 16 KB
    __shared__ __align__(16) unsigned short s_tabh[TAB_N]; // 8 KB
    __shared__ __align__(16) unsigned short s_w2t[H_DIM * W2T_STRIDE]; // 9 KB
    __shared__ __align__(16) float s_w1s[H_DIM];
    __shared__ __align__(16) float s_b1s[H_DIM];
    __shared__ float s_c2[H_DIM];
    __shared__ float s_W3[H_DIM];

    // in-block tanh LUT build (16 evals/thread)
    #pragma unroll
    for (int it = 0; it < TAB_N / 256; ++it) {
        int i = tid + it * 256;
        float c = ((float)(i - 2048) + 0.5f) * (1.0f / 512.0f);
        float v = fast_tanh(c);
        s_tabf[i] = v;
        s_tabh[i] = f2bf(v);
    }

    if (tid < 64) {
        s_w1s[tid] = W1[d * H_DIM + tid] * 512.0f;
        s_b1s[tid] = b1[d * H_DIM + tid] * 512.0f + 2048.0f;
    } else if (tid < 128) {
        int h = tid - 64;
        s_c2[h] = b2[d * H_DIM + h] * 512.0f + 2048.0f;
        s_W3[h] = W3[d * H_DIM + h];
    }
    {
        const float* gW2 = W2 + (size_t)d * H_DIM * H_DIM;   // [h][col]
        #pragma unroll
        for (int i = 0; i < 16; ++i) {
            int idx = tid + i * 256;
            int h = idx >> 6, c = idx & 63;
            s_w2t[c * W2T_STRIDE + h] = f2bf(gW2[idx]);
        }
    }
    __syncthreads();

    float x = (float)(gBase + tid) * (1.0f / FT_SCALE) - 32.0f;

    float xm[4];
    #pragma unroll
    for (int mt = 0; mt < 4; ++mt) xm[mt] = __shfl(x, mt * 16 + l15, 64);

    // layer 1 -> A fragments via bf16 tanh LUT: A[m=l15][k=quad*8+j]
    short8 afrag[4][2];
    #pragma unroll
    for (int ks = 0; ks < 2; ++ks) {
        float w1v[8], b1v[8];
        #pragma unroll
        for (int j = 0; j < 8; ++j) {
            int k = ks * 32 + quad * 8 + j;
            w1v[j] = s_w1s[k];
            b1v[j] = s_b1s[k];
        }
        #pragma unroll
        for (int mt = 0; mt < 4; ++mt) {
            unsigned short hb[8];
            #pragma unroll
            for (int j = 0; j < 8; ++j) {
                float idxf = fmaf(xm[mt], w1v[j], b1v[j]);
                idxf = fminf(fmaxf(idxf, 0.0f), 4095.0f);
                hb[j] = s_tabh[(unsigned int)idxf];
            }
            union { unsigned int u[4]; short8 s; } fr;
            #pragma unroll
            for (int p = 0; p < 4; ++p)
                fr.u[p] = (unsigned int)hb[2*p] | ((unsigned int)hb[2*p+1] << 16);
            afrag[mt][ks] = fr.s;
        }
    }

    short8 bfrag[4][2];
    #pragma unroll
    for (int nt = 0; nt < 4; ++nt)
        #pragma unroll
        for (int ks = 0; ks < 2; ++ks)
            bfrag[nt][ks] = *(const short8*)
                &s_w2t[(nt * 16 + l15) * W2T_STRIDE + ks * 32 + quad * 8];

    float4v acc[4][4];
    #pragma unroll
    for (int mt = 0; mt < 4; ++mt)
        #pragma unroll
        for (int nt = 0; nt < 4; ++nt) {
            float4v c = {0.0f, 0.0f, 0.0f, 0.0f};
            c = __builtin_amdgcn_mfma_f32_16x16x32_bf16(afrag[mt][0], bfrag[nt][0], c, 0, 0, 0);
            c = __builtin_amdgcn_mfma_f32_16x16x32_bf16(afrag[mt][1], bfrag[nt][1], c, 0, 0, 0);
            acc[mt][nt] = c;
        }

    float w3v[4], c2v[4];
    #pragma unroll
    for (int nt = 0; nt < 4; ++nt) {
        int col = nt * 16 + l15;
        w3v[nt] = s_W3[col];
        c2v[nt] = s_c2[col];
    }

    float psum[4][4];
    #pragma unroll
    for (int mt = 0; mt < 4; ++mt)
        #pragma unroll
        for (int r = 0; r < 4; ++r) psum[mt][r] = 0.0f;

    #pragma unroll
    for (int mt = 0; mt < 4; ++mt)
        #pragma unroll
        for (int nt = 0; nt < 4; ++nt)
            #pragma unroll
            for (int r = 0; r < 4; ++r) {
                float idxf = fmaf(acc[mt][nt][r], 512.0f, c2v[nt]);
                idxf = fminf(fmaxf(idxf, 0.0f), 4095.0f);
                psum[mt][r] += s_tabf[(unsigned int)idxf] * w3v[nt];
            }

    #pragma unroll
    for (int mask = 1; mask < 16; mask <<= 1)
        #pragma unroll
        for (int mt = 0; mt < 4; ++mt)
            #pragma unroll
            for (int r = 0; r < 4; ++r)
                psum[mt][r] += __shfl_xor(psum[mt][r], mask, 64);

    const float bias = b3[d];   // wave-uniform scalar load
    #pragma unroll
    for (int mt = 0; mt < 4; ++mt)
        #pragma unroll
        for (int r = 0; r < 4; ++r)
            if (l15 == mt * 4 + r) {
                int row = mt * 16 + quad * 4 + r;
                int gi = gBase + waveId * 64 + row;
                ftab[d * FT_PTS + gi] = psum[mt][r] + bias;
            }
}

// =====================================================================
// decode_k: bx in [0,512): (bx&63) -> 256-sample group, (bx>>6) -> 16
// channels. 16 tables (64 KB contiguous) -> LDS; z in registers;
// 16-float contiguous stores per thread.
// =====================================================================
__global__ __launch_bounds__(256, 2) void decode_k(
    const float* __restrict__ z, const float* __restrict__ W_mix,
    const float* __restrict__ ftab, float* __restrict__ out)
{
    const int bx  = blockIdx.x;
    const int tid = threadIdx.x;
    const int n0 = (bx & 63) * 256;
    const int c0 = (bx >> 6) * 16;

    __shared__ __align__(16) float s_tab[16 * FT_PTS];  // 64 KB
    __shared__ __align__(16) float s_sp[16 * L_DIM];    // 1 KB

    const float4* gt = (const float4*)(ftab + (size_t)c0 * FT_PTS);
    float4* st = (float4*)s_tab;
    #pragma unroll
    for (int j = 0; j < 16; ++j)
        st[tid + j * 256] = gt[tid + j * 256];

    {
        int c = tid >> 4, l = tid & 15;
        s_sp[tid] = softplus_f(W_mix[(c0 + c) * L_DIM + l]);
    }
    __syncthreads();

    const int n = n0 + tid;
    float4 zz[4];
    const float4* zp = (const float4*)(z + (size_t)n * L_DIM);
    #pragma unroll
    for (int i = 0; i < 4; ++i) zz[i] = zp[i];

    float o[16];
    #pragma unroll
    for (int c = 0; c < 16; ++c) {
        const float4* spv = (const float4*)(s_sp + c * 16);  // wave-uniform
        float x = 0.0f;
        #pragma unroll
        for (int i = 0; i < 4; ++i) {
            float4 s = spv[i];
            x = fmaf(zz[i].x, s.x, x);
            x = fmaf(zz[i].y, s.y, x);
            x = fmaf(zz[i].z, s.z, x);
            x = fmaf(zz[i].w, s.w, x);
        }
        float idxf = fmaf(x, FT_SCALE, FT_OFF);
        idxf = fminf(fmaxf(idxf, 0.0f), (float)(FT_PTS - 2));
        int i0 = (int)idxf;
        float fr = idxf - (float)i0;
        const float* tb = s_tab + c * FT_PTS;
        float v0 = tb[i0];
        float v1 = tb[i0 + 1];
        o[c] = fmaf(v1 - v0, fr, v0);
    }

    float4* op = (float4*)(out + (size_t)n * D_DIM + c0);
    #pragma unroll
    for (int q = 0; q < 4; ++q) {
        float4 v;
        v.x = o[4*q+0]; v.y = o[4*q+1]; v.z = o[4*q+2]; v.w = o[4*q+3];
        op[q] = v;
    }
}

extern "C" void kernel_launch(void* const* d_in, const int* in_sizes, int n_in,
                              void* d_out, int out_size, void* d_ws, size_t ws_size,
                              hipStream_t stream) {
    const float* z     = (const float*)d_in[0];
    const float* W_mix = (const float*)d_in[1];
    const float* W1    = (const float*)d_in[2];
    const float* b1    = (const float*)d_in[3];
    const float* W2    = (const float*)d_in[4];
    const float* b2    = (const float*)d_in[5];
    const float* W3    = (const float*)d_in[6];
    const float* b3    = (const float*)d_in[7];
    float* out = (float*)d_out;
    float* ftab = (float*)d_ws;   // 512 KB

    build_k<<<dim3(512), dim3(256), 0, stream>>>(W1, b1, W2, b2, W3, b3, ftab);
    decode_k<<<dim3(512), dim3(256), 0, stream>>>(z, W_mix, ftab, out);
}

// Round 8
// 81.604 us; speedup vs baseline: 2.1636x; 1.0563x over previous
//
#include <hip/hip_runtime.h>
#include <hip/hip_bf16.h>

// Decoder: x = z @ softplus(W_mix)^T ; per-channel MLP 1->H->H->1 with tanh.
// N=16384, L=16, D=128, H=64.
// Round 8 (final): out[n,d] = f_d(x[n,d]) scalar-function factorization.
//   build_k : 256 blocks (d, 256-pt tile of 512) tabulate f_d at 512 pts
//             (step 1/8, [-32,32)) via bf16 MFMA + in-LDS 2048-pt tanh LUT.
//   decode_k: 512 blocks (256 samples x 16 channels); 16 tables (32 KB)
//             staged to LDS, z in registers, 16-float contiguous stores.
// Error budget: bf16-W2 term 0.0156 (measured, dominant); f-interp at
// step 1/8 ~6e-3; tanh-LUT at 1/256 ~2e-3 (below the bf16 quant h1 gets
// anyway). Total < 0.025 << 0.0475 threshold.
// Measured lessons: cg grid.sync costs ~80us (round 6) -- two plain
// launches. Harness floor (ws re-poison fill ~41us + restores + graph
// gaps) ~= 80us; controllable work this round ~3us.

#define N_SAMPLES 16384
#define L_DIM 16
#define D_DIM 128
#define H_DIM 64
#define W2T_STRIDE 72    // ushort elems; 144 B rows, 16B-aligned
#define TAB_N 2048       // tanh LUT: [-4,4], step 1/256
#define FT_PTS 512       // f-table points per channel
#define FT_SCALE 8.0f    // idx = x*8 + 256; step 1/8 over [-32,32)
#define FT_OFF 256.0f

typedef __attribute__((ext_vector_type(8))) short short8;
typedef __attribute__((ext_vector_type(4))) float float4v;

__device__ __forceinline__ float fast_tanh(float x) {
    float e = __expf(2.0f * x);
    return 1.0f - 2.0f * __builtin_amdgcn_rcpf(1.0f + e);
}

__device__ __forceinline__ unsigned short f2bf(float f) {
    union { float f; unsigned int u; } v; v.f = f;
    unsigned int r = (v.u + 0x7fffu + ((v.u >> 16) & 1u)) >> 16;   // RNE
    return (unsigned short)r;
}

__device__ __forceinline__ float softplus_f(float w) {
    return (w > 20.0f) ? w : log1pf(__expf(w));
}

// =====================================================================
// build_k: tabulate f_d at x = gi/8 - 32, gi in [0,512).
// blockIdx.x in [0,256): d = bx>>1, tile = bx&1.
// =====================================================================
__global__ __launch_bounds__(256, 2) void build_k(
    const float* __restrict__ W1, const float* __restrict__ b1,
    const float* __restrict__ W2, const float* __restrict__ b2,
    const float* __restrict__ W3, const float* __restrict__ b3,
    float* __restrict__ ftab)
{
    const int bx     = blockIdx.x;
    const int tid    = threadIdx.x;
    const int d      = bx >> 1;
    const int gBase  = (bx & 1) * 256;
    const int lane   = tid & 63;
    const int waveId = tid >> 6;
    const int quad   = lane >> 4;
    const int l15    = lane & 15;

    __shared__ __align__(16) float s_tabf[TAB_N];          // 8 KB
    __shared__ __align__(16) unsigned short s_tabh[TAB_N]; // 4 KB
    __shared__ __align__(16) unsigned short s_w2t[H_DIM * W2T_STRIDE]; // 9 KB
    __shared__ __align__(16) float s_w1s[H_DIM];   // 256*W1
    __shared__ __align__(16) float s_b1s[H_DIM];   // 256*b1 + 1024
    __shared__ float s_c2[H_DIM];                  // 256*b2 + 1024
    __shared__ float s_W3[H_DIM];

    // in-block tanh LUT build (8 evals/thread), cell-centered on [-4,4]
    #pragma unroll
    for (int it = 0; it < TAB_N / 256; ++it) {
        int i = tid + it * 256;
        float c = ((float)(i - 1024) + 0.5f) * (1.0f / 256.0f);
        float v = fast_tanh(c);
        s_tabf[i] = v;
        s_tabh[i] = f2bf(v);
    }

    if (tid < 64) {
        s_w1s[tid] = W1[d * H_DIM + tid] * 256.0f;
        s_b1s[tid] = b1[d * H_DIM + tid] * 256.0f + 1024.0f;
    } else if (tid < 128) {
        int h = tid - 64;
        s_c2[h] = b2[d * H_DIM + h] * 256.0f + 1024.0f;
        s_W3[h] = W3[d * H_DIM + h];
    }
    {
        const float* gW2 = W2 + (size_t)d * H_DIM * H_DIM;   // [h][col]
        #pragma unroll
        for (int i = 0; i < 16; ++i) {
            int idx = tid + i * 256;
            int h = idx >> 6, c = idx & 63;
            s_w2t[c * W2T_STRIDE + h] = f2bf(gW2[idx]);
        }
    }
    __syncthreads();

    float x = (float)(gBase + tid) * (1.0f / FT_SCALE) - 32.0f;

    float xm[4];
    #pragma unroll
    for (int mt = 0; mt < 4; ++mt) xm[mt] = __shfl(x, mt * 16 + l15, 64);

    // layer 1 -> A fragments via bf16 tanh LUT: A[m=l15][k=quad*8+j]
    short8 afrag[4][2];
    #pragma unroll
    for (int ks = 0; ks < 2; ++ks) {
        float w1v[8], b1v[8];
        #pragma unroll
        for (int j = 0; j < 8; ++j) {
            int k = ks * 32 + quad * 8 + j;
            w1v[j] = s_w1s[k];
            b1v[j] = s_b1s[k];
        }
        #pragma unroll
        for (int mt = 0; mt < 4; ++mt) {
            unsigned short hb[8];
            #pragma unroll
            for (int j = 0; j < 8; ++j) {
                float idxf = fmaf(xm[mt], w1v[j], b1v[j]);
                idxf = fminf(fmaxf(idxf, 0.0f), (float)(TAB_N - 1));
                hb[j] = s_tabh[(unsigned int)idxf];
            }
            union { unsigned int u[4]; short8 s; } fr;
            #pragma unroll
            for (int p = 0; p < 4; ++p)
                fr.u[p] = (unsigned int)hb[2*p] | ((unsigned int)hb[2*p+1] << 16);
            afrag[mt][ks] = fr.s;
        }
    }

    short8 bfrag[4][2];
    #pragma unroll
    for (int nt = 0; nt < 4; ++nt)
        #pragma unroll
        for (int ks = 0; ks < 2; ++ks)
            bfrag[nt][ks] = *(const short8*)
                &s_w2t[(nt * 16 + l15) * W2T_STRIDE + ks * 32 + quad * 8];

    float4v acc[4][4];
    #pragma unroll
    for (int mt = 0; mt < 4; ++mt)
        #pragma unroll
        for (int nt = 0; nt < 4; ++nt) {
            float4v c = {0.0f, 0.0f, 0.0f, 0.0f};
            c = __builtin_amdgcn_mfma_f32_16x16x32_bf16(afrag[mt][0], bfrag[nt][0], c, 0, 0, 0);
            c = __builtin_amdgcn_mfma_f32_16x16x32_bf16(afrag[mt][1], bfrag[nt][1], c, 0, 0, 0);
            acc[mt][nt] = c;
        }

    float w3v[4], c2v[4];
    #pragma unroll
    for (int nt = 0; nt < 4; ++nt) {
        int col = nt * 16 + l15;
        w3v[nt] = s_W3[col];
        c2v[nt] = s_c2[col];
    }

    float psum[4][4];
    #pragma unroll
    for (int mt = 0; mt < 4; ++mt)
        #pragma unroll
        for (int r = 0; r < 4; ++r) psum[mt][r] = 0.0f;

    #pragma unroll
    for (int mt = 0; mt < 4; ++mt)
        #pragma unroll
        for (int nt = 0; nt < 4; ++nt)
            #pragma unroll
            for (int r = 0; r < 4; ++r) {
                float idxf = fmaf(acc[mt][nt][r], 256.0f, c2v[nt]);
                idxf = fminf(fmaxf(idxf, 0.0f), (float)(TAB_N - 1));
                psum[mt][r] += s_tabf[(unsigned int)idxf] * w3v[nt];
            }

    #pragma unroll
    for (int mask = 1; mask < 16; mask <<= 1)
        #pragma unroll
        for (int mt = 0; mt < 4; ++mt)
            #pragma unroll
            for (int r = 0; r < 4; ++r)
                psum[mt][r] += __shfl_xor(psum[mt][r], mask, 64);

    const float bias = b3[d];   // wave-uniform scalar load
    #pragma unroll
    for (int mt = 0; mt < 4; ++mt)
        #pragma unroll
        for (int r = 0; r < 4; ++r)
            if (l15 == mt * 4 + r) {
                int row = mt * 16 + quad * 4 + r;
                int gi = gBase + waveId * 64 + row;
                ftab[d * FT_PTS + gi] = psum[mt][r] + bias;
            }
}

// =====================================================================
// decode_k: bx in [0,512): (bx&63) -> 256-sample group, (bx>>6) -> 16
// channels. 16 tables (32 KB contiguous) -> LDS; z in registers;
// 16-float contiguous stores per thread. 4 blocks/CU.
// =====================================================================
__global__ __launch_bounds__(256, 4) void decode_k(
    const float* __restrict__ z, const float* __restrict__ W_mix,
    const float* __restrict__ ftab, float* __restrict__ out)
{
    const int bx  = blockIdx.x;
    const int tid = threadIdx.x;
    const int n0 = (bx & 63) * 256;
    const int c0 = (bx >> 6) * 16;

    __shared__ __align__(16) float s_tab[16 * FT_PTS];  // 32 KB
    __shared__ __align__(16) float s_sp[16 * L_DIM];    // 1 KB

    const float4* gt = (const float4*)(ftab + (size_t)c0 * FT_PTS);
    float4* st = (float4*)s_tab;
    #pragma unroll
    for (int j = 0; j < 8; ++j)
        st[tid + j * 256] = gt[tid + j * 256];

    {
        int c = tid >> 4, l = tid & 15;
        s_sp[tid] = softplus_f(W_mix[(c0 + c) * L_DIM + l]);
    }
    __syncthreads();

    const int n = n0 + tid;
    float4 zz[4];
    const float4* zp = (const float4*)(z + (size_t)n * L_DIM);
    #pragma unroll
    for (int i = 0; i < 4; ++i) zz[i] = zp[i];

    float o[16];
    #pragma unroll
    for (int c = 0; c < 16; ++c) {
        const float4* spv = (const float4*)(s_sp + c * 16);  // wave-uniform
        float x = 0.0f;
        #pragma unroll
        for (int i = 0; i < 4; ++i) {
            float4 s = spv[i];
            x = fmaf(zz[i].x, s.x, x);
            x = fmaf(zz[i].y, s.y, x);
            x = fmaf(zz[i].z, s.z, x);
            x = fmaf(zz[i].w, s.w, x);
        }
        float idxf = fmaf(x, FT_SCALE, FT_OFF);
        idxf = fminf(fmaxf(idxf, 0.0f), (float)(FT_PTS - 2));
        int i0 = (int)idxf;
        float fr = idxf - (float)i0;
        const float* tb = s_tab + c * FT_PTS;
        float v0 = tb[i0];
        float v1 = tb[i0 + 1];
        o[c] = fmaf(v1 - v0, fr, v0);
    }

    float4* op = (float4*)(out + (size_t)n * D_DIM + c0);
    #pragma unroll
    for (int q = 0; q < 4; ++q) {
        float4 v;
        v.x = o[4*q+0]; v.y = o[4*q+1]; v.z = o[4*q+2]; v.w = o[4*q+3];
        op[q] = v;
    }
}

extern "C" void kernel_launch(void* const* d_in, const int* in_sizes, int n_in,
                              void* d_out, int out_size, void* d_ws, size_t ws_size,
                              hipStream_t stream) {
    const float* z     = (const float*)d_in[0];
    const float* W_mix = (const float*)d_in[1];
    const float* W1    = (const float*)d_in[2];
    const float* b1    = (const float*)d_in[3];
    const float* W2    = (const float*)d_in[4];
    const float* b2    = (const float*)d_in[5];
    const float* W3    = (const float*)d_in[6];
    const float* b3    = (const float*)d_in[7];
    float* out = (float*)d_out;
    float* ftab = (float*)d_ws;   // 256 KB

    build_k<<<dim3(256), dim3(256), 0, stream>>>(W1, b1, W2, b2, W3, b3, ftab);
    decode_k<<<dim3(512), dim3(256), 0, stream>>>(z, W_mix, ftab, out);
}